// Round 3
// baseline (197.989 us; speedup 1.0000x reference)
//
#include <hip/hip_runtime.h>
#include <math.h>

#define W 1024
#define IMG_SZ (1024*1024)
#define N_IMG 32
#define RPC 16                      // rows per chunk
#define CPI 64                      // chunks per image
#define TOTAL_CHUNKS (N_IMG*CPI)    // 2048

// curv = Dxy*(Dx-Dy)^2 / (2h*(Dx^2+Dy^2)^1.5 + 16 h^4 * 1e-8)
#define TWO_H    0.122f
#define C_EPS    2.2153332e-12f     // 16 * 0.061^4 * 1e-8

struct Row { float e[6]; };          // e[0]=x-1 halo, e[1..4]=float4, e[5]=x+4 halo

__device__ __forceinline__ void load_row(const float* __restrict__ img, int y,
                                         int xbase, int lane, int q, Row& r) {
    const float* p = img + (size_t)y * W + xbase;
    const float4 v = *reinterpret_cast<const float4*>(p);
    float hl = 0.0f, hr = 0.0f;
    if (lane == 0 && q != 0)    hl = p[-1];    // wave-left halo (exec-masked load)
    if (lane == 63 && q != 255) hr = p[4];     // wave-right halo
    const float a0 = __shfl_up(v.w, 1, 64);    // neighbor lane's last element
    const float a5 = __shfl_down(v.x, 1, 64);  // neighbor lane's first element
    r.e[0] = (lane == 0)  ? hl : a0;
    r.e[1] = v.x; r.e[2] = v.y; r.e[3] = v.z; r.e[4] = v.w;
    r.e[5] = (lane == 63) ? hr : a5;
}

__device__ __forceinline__ void pixel(const Row& T, const Row& M, const Row& B,
                                      int j, bool ok, float& fsum, int& cnt) {
    const float Dx  = M.e[j+2] - M.e[j];
    const float Dy  = B.e[j+1] - T.e[j+1];
    const float Dxy = (B.e[j+2] - B.e[j]) - T.e[j+2] + T.e[j];
    const float dif = Dx - Dy;
    const float num = Dxy * (dif * dif);
    const float s   = Dx*Dx + Dy*Dy;
    const float den = TWO_H * (s * __builtin_amdgcn_sqrtf(s)) + C_EPS;
    const float t   = num * __builtin_amdgcn_rcpf(den);
    const float cr  = fmaxf(t*t - 1.0f, 0.0f);
    const float c  = M.e[j+1];
    const float pm = fminf(fminf(c*M.e[j+2], c*M.e[j]),
                           fminf(c*B.e[j+1], c*T.e[j+1]));
    const bool take = (pm < 0.0f) & ok;
    fsum += take ? cr : 0.0f;
    cnt  += take ? 1 : 0;
}

__device__ __forceinline__ void do_row(const Row& T, const Row& M, const Row& B,
                                       int q, float& fsum, int& cnt) {
    pixel(T, M, B, 0, q != 0,   fsum, cnt);   // x = 4q   (invalid only at x=0)
    pixel(T, M, B, 1, true,     fsum, cnt);
    pixel(T, M, B, 2, true,     fsum, cnt);
    pixel(T, M, B, 3, q != 255, fsum, cnt);   // x = 4q+3 (invalid only at x=1023)
}

__global__ __launch_bounds__(256) void curv_partial(const float* __restrict__ phi,
                                                    double* __restrict__ partial,
                                                    int nb) {
    const int q = threadIdx.x;        // quad id 0..255, pixels x = 4q..4q+3
    const int lane = q & 63;
    const int xbase = q * 4;
    double sum = 0.0, dcnt = 0.0;

    for (int chunk = (int)blockIdx.x; chunk < TOTAL_CHUNKS; chunk += nb) {
        const int n  = chunk >> 6;
        const int ci = chunk & 63;
        const int y0 = 1 + ci * RPC;
        const int yend = (y0 + RPC < 1023) ? (y0 + RPC) : 1023;  // exclusive
        const float* img = phi + (size_t)n * IMG_SZ;

        float fsum = 0.0f;
        int cnt = 0;

        Row A, Bv, C;
        load_row(img, y0 - 1, xbase, lane, q, A);
        load_row(img, y0,     xbase, lane, q, Bv);

        // 3-row ring, roles rotate each body: no register-shuffle movs.
        for (int y = y0; y < yend; y += 3) {
            load_row(img, y + 1, xbase, lane, q, C);
            do_row(A, Bv, C, q, fsum, cnt);
            if (y + 1 < yend) {
                load_row(img, y + 2, xbase, lane, q, A);
                do_row(Bv, C, A, q, fsum, cnt);
            }
            if (y + 2 < yend) {
                load_row(img, y + 3, xbase, lane, q, Bv);
                do_row(C, A, Bv, q, fsum, cnt);
            }
        }
        sum  += (double)fsum;
        dcnt += (double)cnt;
    }

    // wave (64-lane) shuffle reduction
    for (int off = 32; off > 0; off >>= 1) {
        sum  += __shfl_down(sum, off, 64);
        dcnt += __shfl_down(dcnt, off, 64);
    }
    __shared__ double lsum[4], lcnt[4];
    const int wave = threadIdx.x >> 6;
    if (lane == 0) { lsum[wave] = sum; lcnt[wave] = dcnt; }
    __syncthreads();
    if (threadIdx.x == 0) {
        partial[blockIdx.x]      = lsum[0] + lsum[1] + lsum[2] + lsum[3];
        partial[nb + blockIdx.x] = lcnt[0] + lcnt[1] + lcnt[2] + lcnt[3];
    }
}

__global__ __launch_bounds__(256) void curv_final(const double* __restrict__ partial,
                                                  int nb, float* __restrict__ out) {
    double s = 0.0, c = 0.0;
    for (int i = threadIdx.x; i < nb; i += 256) {
        s += partial[i];
        c += partial[nb + i];
    }
    for (int off = 32; off > 0; off >>= 1) {
        s += __shfl_down(s, off, 64);
        c += __shfl_down(c, off, 64);
    }
    __shared__ double lsum[4], lcnt[4];
    const int lane = threadIdx.x & 63, wave = threadIdx.x >> 6;
    if (lane == 0) { lsum[wave] = s; lcnt[wave] = c; }
    __syncthreads();
    if (threadIdx.x == 0) {
        const double S = lsum[0] + lsum[1] + lsum[2] + lsum[3];
        const double C = lcnt[0] + lcnt[1] + lcnt[2] + lcnt[3];
        out[0] = (float)(S / (C + 1e-8));
    }
}

extern "C" void kernel_launch(void* const* d_in, const int* in_sizes, int n_in,
                              void* d_out, int out_size, void* d_ws, size_t ws_size,
                              hipStream_t stream) {
    const float* phi = (const float*)d_in[0];
    float* out = (float*)d_out;
    double* partial = (double*)d_ws;

    int nb = TOTAL_CHUNKS;
    const size_t need = (size_t)nb * 2 * sizeof(double);
    if (ws_size < need) {
        nb = (int)(ws_size / (2 * sizeof(double)));
        if (nb < 1) nb = 1;
    }

    curv_partial<<<nb, 256, 0, stream>>>(phi, partial, nb);
    curv_final<<<1, 256, 0, stream>>>(partial, nb, out);
}

// Round 4
// 195.626 us; speedup vs baseline: 1.0121x; 1.0121x over previous
//
#include <hip/hip_runtime.h>
#include <math.h>
#include <float.h>

#define W 1024
#define IMG_SZ (1024*1024)
#define N_PAIR 16                     // image pairs (n, n+16)
#define RPC 8                         // rows per chunk
#define CPI 128                       // ceil(1022/8)
#define TOTAL_CHUNKS (N_PAIR*CPI)     // 2048

// curv = Dxy*(Dx-Dy)^2 / (2h*(Dx^2+Dy^2)^1.5 + 16 h^4 * 1e-8)
#define TWO_H    0.122f
#define C_EPS    2.2153332e-12f       // 16 * 0.061^4 * 1e-8

typedef float f2 __attribute__((ext_vector_type(2)));

// Row window [x-1 .. x+4] for two images packed in f2 lanes.
__device__ __forceinline__ void load_row(const float* __restrict__ pa,
                                         const float* __restrict__ pb,
                                         f2 r[6], int q) {
    const float4 va = *reinterpret_cast<const float4*>(pa);
    const float4 vb = *reinterpret_cast<const float4*>(pb);
    r[1].x = va.x; r[1].y = vb.x;
    r[2].x = va.y; r[2].y = vb.y;
    r[3].x = va.z; r[3].y = vb.z;
    r[4].x = va.w; r[4].y = vb.w;
    f2 L = {0.0f, 0.0f}, R = {0.0f, 0.0f};
    if (q != 0)   { L.x = pa[-1]; L.y = pb[-1]; }
    if (q != 255) { R.x = pa[4];  R.y = pb[4]; }
    r[0] = L; r[5] = R;
}

// Two pixels (same x,y, two images). EDGED: apply edge mask (j==0 or j==3).
template<bool EDGED>
__device__ __forceinline__ void pixpair(const f2* __restrict__ T, const f2* __restrict__ M,
                                        const f2* __restrict__ B, int j, float edge,
                                        float& fsum, int& cnt) {
    const f2 Dx  = M[j+2] - M[j];
    const f2 Dy  = B[j+1] - T[j+1];
    const f2 Dxy = (B[j+2] - B[j]) - T[j+2] + T[j];
    const f2 dif = Dx - Dy;
    const f2 num = Dxy * (dif * dif);
    const f2 s   = Dx*Dx + Dy*Dy;
    f2 sq;
    sq.x = __builtin_amdgcn_sqrtf(s.x);
    sq.y = __builtin_amdgcn_sqrtf(s.y);
    const f2 twoh = {TWO_H, TWO_H};
    const f2 epsv = {C_EPS, C_EPS};
    const f2 den  = twoh * (s * sq) + epsv;
    // one reciprocal for both pixels: den >= eps so dd >= eps^2 > 0 (no underflow)
    const float dd = den.x * den.y;
    const float rc = __builtin_amdgcn_rcpf(dd);
    const float t0 = num.x * (den.y * rc);
    const float t1 = num.y * (den.x * rc);
    const float cr0 = fmaxf(t0*t0 - 1.0f, 0.0f);
    const float cr1 = fmaxf(t1*t1 - 1.0f, 0.0f);
    const f2 c  = M[j+1];
    const f2 p1 = c * M[j];
    const f2 p2 = c * M[j+2];
    const f2 p3 = c * T[j+1];
    const f2 p4 = c * B[j+1];
    float mn0 = fminf(fminf(p1.x, p2.x), fminf(p3.x, p4.x));
    float mn1 = fminf(fminf(p1.y, p2.y), fminf(p3.y, p4.y));
    if (EDGED) { mn0 = fmaxf(mn0, edge); mn1 = fmaxf(mn1, edge); }
    const bool k0 = mn0 < 0.0f;
    const bool k1 = mn1 < 0.0f;
    fsum += k0 ? cr0 : 0.0f;
    fsum += k1 ? cr1 : 0.0f;
    cnt += __popcll(__ballot(k0));    // scalar-pipe wave popcount (wave-uniform cnt)
    cnt += __popcll(__ballot(k1));
}

__device__ __forceinline__ void do_row(const f2* T, const f2* M, const f2* B,
                                       float edge0, float edge3,
                                       float& fsum, int& cnt) {
    pixpair<true >(T, M, B, 0, edge0, fsum, cnt);
    pixpair<false>(T, M, B, 1, 0.0f,  fsum, cnt);
    pixpair<false>(T, M, B, 2, 0.0f,  fsum, cnt);
    pixpair<true >(T, M, B, 3, edge3, fsum, cnt);
}

__global__ __launch_bounds__(256) void curv_partial(const float* __restrict__ phi,
                                                    double* __restrict__ partial,
                                                    int nb) {
    const int q = threadIdx.x;             // 0..255, pixels x = 4q..4q+3
    const int xbase = q * 4;
    const float edge0 = (q == 0)   ? 1.0f : -FLT_MAX;   // x=0 invalid
    const float edge3 = (q == 255) ? 1.0f : -FLT_MAX;   // x=1023 invalid
    double sum = 0.0, dcnt = 0.0;

    for (int chunk = (int)blockIdx.x; chunk < TOTAL_CHUNKS; chunk += nb) {
        const int p  = chunk >> 7;         // image pair 0..15
        const int ci = chunk & 127;        // row-chunk 0..127
        const int y0 = 1 + ci * RPC;
        const int nrows = (1023 - y0 < RPC) ? (1023 - y0) : RPC;
        const float* pa = phi + (size_t)p        * IMG_SZ + (size_t)(y0-1) * W + xbase;
        const float* pb = phi + (size_t)(p + 16) * IMG_SZ + (size_t)(y0-1) * W + xbase;

        float fsum = 0.0f;
        int cnt = 0;

        f2 R0[6], R1[6], R2[6];
        load_row(pa, pb, R0, q); pa += W; pb += W;
        load_row(pa, pb, R1, q); pa += W; pb += W;

#pragma unroll
        for (int rr = 0; rr < RPC; rr += 3) {
            if (rr < nrows) {
                load_row(pa, pb, R2, q); pa += W; pb += W;
                do_row(R0, R1, R2, edge0, edge3, fsum, cnt);
            }
            if (rr + 1 < nrows) {
                load_row(pa, pb, R0, q); pa += W; pb += W;
                do_row(R1, R2, R0, edge0, edge3, fsum, cnt);
            }
            if (rr + 2 < nrows) {
                load_row(pa, pb, R1, q); pa += W; pb += W;
                do_row(R2, R0, R1, edge0, edge3, fsum, cnt);
            }
        }
        sum  += (double)fsum;
        dcnt += (double)cnt;   // wave-uniform
    }

    // fsum: shuffle-reduce across the wave; cnt is already wave-uniform.
    for (int off = 32; off > 0; off >>= 1)
        sum += __shfl_down(sum, off, 64);
    __shared__ double lsum[4], lcnt[4];
    const int lane = q & 63, wv = q >> 6;
    if (lane == 0) { lsum[wv] = sum; lcnt[wv] = dcnt; }
    __syncthreads();
    if (q == 0) {
        partial[blockIdx.x]      = lsum[0] + lsum[1] + lsum[2] + lsum[3];
        partial[nb + blockIdx.x] = lcnt[0] + lcnt[1] + lcnt[2] + lcnt[3];
    }
}

__global__ __launch_bounds__(256) void curv_final(const double* __restrict__ partial,
                                                  int nb, float* __restrict__ out) {
    double s = 0.0, c = 0.0;
    for (int i = threadIdx.x; i < nb; i += 256) {
        s += partial[i];
        c += partial[nb + i];
    }
    for (int off = 32; off > 0; off >>= 1) {
        s += __shfl_down(s, off, 64);
        c += __shfl_down(c, off, 64);
    }
    __shared__ double lsum[4], lcnt[4];
    const int lane = threadIdx.x & 63, wv = threadIdx.x >> 6;
    if (lane == 0) { lsum[wv] = s; lcnt[wv] = c; }
    __syncthreads();
    if (threadIdx.x == 0) {
        const double S = lsum[0] + lsum[1] + lsum[2] + lsum[3];
        const double C = lcnt[0] + lcnt[1] + lcnt[2] + lcnt[3];
        out[0] = (float)(S / (C + 1e-8));
    }
}

extern "C" void kernel_launch(void* const* d_in, const int* in_sizes, int n_in,
                              void* d_out, int out_size, void* d_ws, size_t ws_size,
                              hipStream_t stream) {
    const float* phi = (const float*)d_in[0];
    float* out = (float*)d_out;
    double* partial = (double*)d_ws;

    int nb = TOTAL_CHUNKS;
    const size_t need = (size_t)nb * 2 * sizeof(double);
    if (ws_size < need) {
        nb = (int)(ws_size / (2 * sizeof(double)));
        if (nb < 1) nb = 1;
    }

    curv_partial<<<nb, 256, 0, stream>>>(phi, partial, nb);
    curv_final<<<1, 256, 0, stream>>>(partial, nb, out);
}

// Round 5
// 194.873 us; speedup vs baseline: 1.0160x; 1.0039x over previous
//
#include <hip/hip_runtime.h>
#include <math.h>
#include <float.h>

#define W 1024
#define IMG_SZ (1024*1024)
#define N_IMG 32
#define RPC 6                          // interior rows computed per chunk
#define TROWS (RPC+2)                  // 8 rows staged (32 KB LDS)
#define CPI 171                        // ceil(1022/6)
#define TOTAL_CHUNKS (N_IMG*CPI)       // 5472

// curv = Dxy*(Dx-Dy)^2 / (2h*(Dx^2+Dy^2)^1.5 + 16 h^4 * 1e-8)
#define TWO_H    0.122f
#define C_EPS    2.2153332e-12f        // 16 * 0.061^4 * 1e-8

typedef const __attribute__((address_space(1))) void* gas_p;
typedef __attribute__((address_space(3))) void*       las_p;

__device__ __forceinline__ void gload_lds16(const float* gp, float* lp) {
    __builtin_amdgcn_global_load_lds((gas_p)gp, (las_p)lp, 16, 0, 0);
}

struct Px { float num, den, mn; };

__device__ __forceinline__ Px px(const float T[6], const float M[6], const float B[6], int j) {
    Px p;
    const float Dx  = M[j+2] - M[j];
    const float Dy  = B[j+1] - T[j+1];
    const float Dxy = (B[j+2] - B[j]) - T[j+2] + T[j];
    const float dif = Dx - Dy;
    p.num = Dxy * (dif * dif);
    const float s = Dx*Dx + Dy*Dy;
    p.den = TWO_H * (s * __builtin_amdgcn_sqrtf(s)) + C_EPS;
    const float c = M[j+1];
    p.mn = fminf(fminf(c*M[j], c*M[j+2]), fminf(c*T[j+1], c*B[j+1]));
    return p;
}

// shared reciprocal for two pixels: den>=C_EPS so den*den >= 4.9e-24 (no underflow)
__device__ __forceinline__ void pair(const Px& a, const Px& b, float ea, float eb,
                                     float& fsum, int& cnt) {
    const float rc = __builtin_amdgcn_rcpf(a.den * b.den);
    const float t0 = a.num * (b.den * rc);
    const float t1 = b.num * (a.den * rc);
    const float cr0 = fmaxf(t0*t0 - 1.0f, 0.0f);
    const float cr1 = fmaxf(t1*t1 - 1.0f, 0.0f);
    const bool k0 = fmaxf(a.mn, ea) < 0.0f;
    const bool k1 = fmaxf(b.mn, eb) < 0.0f;
    fsum += k0 ? cr0 : 0.0f;
    fsum += k1 ? cr1 : 0.0f;
    cnt += __popcll(__ballot(k0));     // scalar-pipe; cnt becomes wave-uniform
    cnt += __popcll(__ballot(k1));
}

__device__ __forceinline__ void do_row(const float T[6], const float M[6], const float B[6],
                                       float e0, float e3, float& fsum, int& cnt) {
    const Px p0 = px(T, M, B, 0);
    const Px p1 = px(T, M, B, 1);
    const Px p2 = px(T, M, B, 2);
    const Px p3 = px(T, M, B, 3);
    pair(p0, p1, e0,      -FLT_MAX, fsum, cnt);
    pair(p2, p3, -FLT_MAX, e3,      fsum, cnt);
}

__device__ __forceinline__ void read_win(const float* tile, int rr, int x4,
                                         int ixl, int ixr, float w[6]) {
    const float* row = tile + rr * W;
    const float4 v = *reinterpret_cast<const float4*>(row + x4);  // ds_read_b128
    w[1] = v.x; w[2] = v.y; w[3] = v.z; w[4] = v.w;
    w[0] = row[ixl];
    w[5] = row[ixr];
}

__global__ __launch_bounds__(256, 4) void curv_partial(const float* __restrict__ phi,
                                                       double* __restrict__ partial, int nb) {
    __shared__ float tile[TROWS * W];       // 32 KB
    const int q = threadIdx.x;              // pixels x = 4q..4q+3
    const int lane = q & 63;
    const int wv = q >> 6;
    const int x4 = q * 4;
    const int ixl = (x4 > 0) ? x4 - 1 : 0;          // clamped halo indices (edge-masked later)
    const int ixr = (x4 + 4 < W) ? x4 + 4 : W - 1;
    const float edge0 = (q == 0)   ? 1.0f : -FLT_MAX;   // kills x=0
    const float edge3 = (q == 255) ? 1.0f : -FLT_MAX;   // kills x=1023

    double sum = 0.0, dcnt = 0.0;

    for (int chunk = (int)blockIdx.x; chunk < TOTAL_CHUNKS; chunk += nb) {
        const int n  = chunk / CPI;
        const int ci = chunk - n * CPI;
        const int y0 = 1 + ci * RPC;
        const int nri = (RPC < 1023 - y0) ? RPC : (1023 - y0);   // interior rows this chunk
        const float* img = phi + (size_t)n * IMG_SZ;

        // ---- async stage TROWS rows into LDS: wave wv stages rows 2wv, 2wv+1 ----
#pragma unroll
        for (int rr = 0; rr < 2; ++rr) {
            const int r = wv * 2 + rr;
            int rowg = y0 - 1 + r;
            if (rowg > 1023) rowg = 1023;            // clamp (tail chunk)
            const float* gp = img + (size_t)rowg * W + lane * 4;
            float* lp = &tile[r * W + lane * 4];
#pragma unroll
            for (int o = 0; o < 4; ++o)
                gload_lds16(gp + o * 256, lp + o * 256);
        }
        __builtin_amdgcn_s_waitcnt(0);               // drain global_load_lds
        __syncthreads();

        // ---- compute from LDS: 3-row register ring ----
        float fsum = 0.0f;
        int cnt = 0;
        float R0[6], R1[6], R2[6];
        read_win(tile, 0, x4, ixl, ixr, R0);
        read_win(tile, 1, x4, ixl, ixr, R1);
#pragma unroll
        for (int rr = 0; rr < RPC; rr += 3) {
            if (rr < nri) {
                read_win(tile, rr + 2, x4, ixl, ixr, R2);
                do_row(R0, R1, R2, edge0, edge3, fsum, cnt);
            }
            if (rr + 1 < nri) {
                read_win(tile, rr + 3, x4, ixl, ixr, R0);
                do_row(R1, R2, R0, edge0, edge3, fsum, cnt);
            }
            if (rr + 2 < nri) {
                read_win(tile, rr + 4, x4, ixl, ixr, R1);
                do_row(R2, R0, R1, edge0, edge3, fsum, cnt);
            }
        }
        sum  += (double)fsum;
        dcnt += (double)cnt;                         // wave-uniform
        __syncthreads();                             // protect tile for next chunk (fallback path)
    }

    // fsum: shuffle-reduce; cnt already wave-uniform
    for (int off = 32; off > 0; off >>= 1)
        sum += __shfl_down(sum, off, 64);
    __shared__ double lsum[4], lcnt[4];
    if (lane == 0) { lsum[wv] = sum; lcnt[wv] = dcnt; }
    __syncthreads();
    if (q == 0) {
        partial[blockIdx.x]      = lsum[0] + lsum[1] + lsum[2] + lsum[3];
        partial[nb + blockIdx.x] = lcnt[0] + lcnt[1] + lcnt[2] + lcnt[3];
    }
}

__global__ __launch_bounds__(256) void curv_final(const double* __restrict__ partial,
                                                  int nb, float* __restrict__ out) {
    double s = 0.0, c = 0.0;
    for (int i = threadIdx.x; i < nb; i += 256) {
        s += partial[i];
        c += partial[nb + i];
    }
    for (int off = 32; off > 0; off >>= 1) {
        s += __shfl_down(s, off, 64);
        c += __shfl_down(c, off, 64);
    }
    __shared__ double lsum[4], lcnt[4];
    const int lane = threadIdx.x & 63, wv = threadIdx.x >> 6;
    if (lane == 0) { lsum[wv] = s; lcnt[wv] = c; }
    __syncthreads();
    if (threadIdx.x == 0) {
        const double S = lsum[0] + lsum[1] + lsum[2] + lsum[3];
        const double C = lcnt[0] + lcnt[1] + lcnt[2] + lcnt[3];
        out[0] = (float)(S / (C + 1e-8));
    }
}

extern "C" void kernel_launch(void* const* d_in, const int* in_sizes, int n_in,
                              void* d_out, int out_size, void* d_ws, size_t ws_size,
                              hipStream_t stream) {
    const float* phi = (const float*)d_in[0];
    float* out = (float*)d_out;
    double* partial = (double*)d_ws;

    int nb = TOTAL_CHUNKS;
    const size_t need = (size_t)nb * 2 * sizeof(double);
    if (ws_size < need) {
        nb = (int)(ws_size / (2 * sizeof(double)));
        if (nb < 1) nb = 1;
    }

    curv_partial<<<nb, 256, 0, stream>>>(phi, partial, nb);
    curv_final<<<1, 256, 0, stream>>>(partial, nb, out);
}